// Round 7
// baseline (856.131 us; speedup 1.0000x reference)
//
#include <hip/hip_runtime.h>
#include <math.h>

#define HW 4096
#define BB 32
#define EPSV 1e-5f

typedef _Float16 half8 __attribute__((ext_vector_type(8)));
typedef float f32x4 __attribute__((ext_vector_type(4)));
union H8 { half8 v; ushort4 q[2]; uint4 u4; };

__device__ __forceinline__ float tofloat(const float& v) { return v; }
__device__ __forceinline__ float tofloat(const _Float16& v) { return (float)v; }

// ---------------- bn stats: partial + reduce ----------------
template <typename T>
__global__ __launch_bounds__(256) void bn_partial_kernel(
    const T* __restrict__ x, int C, float* __restrict__ pstat) {
  int c = blockIdx.x, s = blockIdx.y;
  int tid = threadIdx.x;
  float sm = 0.f, s2 = 0.f;
  for (int b = s * 4; b < s * 4 + 4; b++) {
    const T* p = x + ((size_t)b * C + c) * HW;
    for (int i = tid; i < HW; i += 256) { float t = tofloat(p[i]); sm += t; s2 += t * t; }
  }
  __shared__ float sh[2][256];
  sh[0][tid] = sm; sh[1][tid] = s2;
  __syncthreads();
  for (int off = 128; off > 0; off >>= 1) {
    if (tid < off) { sh[0][tid] += sh[0][tid + off]; sh[1][tid] += sh[1][tid + off]; }
    __syncthreads();
  }
  if (tid == 0) {
    pstat[((size_t)s * 64 + c) * 2] = sh[0][0];
    pstat[((size_t)s * 64 + c) * 2 + 1] = sh[1][0];
  }
}

__global__ void bn_reduce_kernel(const float* __restrict__ pstat, float N,
                                 float* __restrict__ mean, float* __restrict__ rstd) {
  int c = threadIdx.x;  // 64
  float s = 0.f, s2 = 0.f;
  for (int k = 0; k < 8; k++) {
    s += pstat[((size_t)k * 64 + c) * 2];
    s2 += pstat[((size_t)k * 64 + c) * 2 + 1];
  }
  float m = s / N;
  mean[c] = m;
  rstd[c] = rsqrtf(s2 / N - m * m + EPSV);
}

// ---------------- pack static conv weights into MFMA A-fragment order ----------------
// wpk[br][chunk14][tap9][lane64][j8]; A row o = chunk*16+(lane&15); k(c) = j<4 ? 4g+j : 16+4g+j-4
__global__ __launch_bounds__(256) void pack_static_kernel(
    const float* __restrict__ wk1c1, const float* __restrict__ wk1c2,
    const float* __restrict__ wk2c1, const float* __restrict__ wk2c2,
    const float* __restrict__ wconv, _Float16* __restrict__ wpk) {
  int idx = blockIdx.x * 256 + threadIdx.x;  // 258048
  int j = idx & 7, lane = (idx >> 3) & 63;
  int tap = (idx >> 9) % 9;
  int chunk = (idx / 4608) % 14;
  int br = idx / 64512;
  int g = lane >> 4;
  int c = (j < 4) ? 4 * g + j : 16 + 4 * g + (j - 4);
  const float* src; int ol0;
  if (chunk < 2)       { src = wk1c1 + (size_t)br * 32 * 288; ol0 = chunk * 16; }
  else if (chunk < 6)  { src = wk1c2 + (size_t)br * 64 * 288; ol0 = (chunk - 2) * 16; }
  else if (chunk < 8)  { src = wk2c1 + (size_t)br * 32 * 288; ol0 = (chunk - 6) * 16; }
  else if (chunk < 12) { src = wk2c2 + (size_t)br * 64 * 288; ol0 = (chunk - 8) * 16; }
  else                 { src = wconv + (size_t)br * 32 * 288; ol0 = (chunk - 12) * 16; }
  int o = ol0 + (lane & 15);
  wpk[idx] = (_Float16)(src[((size_t)o * 32 + c) * 9 + tap]);
}

// ---------------- MFMA conv: 9 shifted K=32 GEMMs; chunk-split over blockIdx.z ----------------
// MODE0 = 5 static convs (affine folded from bn stats), MODE1 = per-sample dynamic conv
template <int MODE>
__global__ __launch_bounds__(256) void conv_mfma_kernel(
    const float* __restrict__ xin, int ch0,
    const _Float16* __restrict__ cin,
    const _Float16* __restrict__ wpk,
    const float* __restrict__ mean, const float* __restrict__ rstd,
    const float* __restrict__ a_pre, int branch,
    _Float16* __restrict__ o0, _Float16* __restrict__ o1,
    _Float16* __restrict__ o2, _Float16* __restrict__ o3,
    _Float16* __restrict__ o4) {
  const int NC_ALL = (MODE == 0) ? 14 : 4;
  const int NC_HALF = NC_ALL / 2;
  __shared__ _Float16 hsh[6 * 66 * 36];  // [row6][col66][c-pad36]
  __shared__ float alsh[32], besh[32];
  int tid = threadIdx.x;
  int b = blockIdx.y, r0 = blockIdx.x * 4, bz = blockIdx.z;
  if (MODE == 0 && tid < 32) {  // fold bn + shortcut into per-channel affine
    float ap = a_pre[branch];
    float r = rstd[ch0 + tid], m = mean[ch0 + tid];
    alsh[tid] = 0.5f * r + 0.01f * ap;
    besh[tid] = -0.5f * m * r;
  }
  __syncthreads();
  for (int t = tid; t < 384; t += 256) {  // zero halo cols
    int row = t >> 6, colh = ((t & 63) >> 5) ? 65 : 0, c = t & 31;
    hsh[(row * 66 + colh) * 36 + c] = (_Float16)0.f;
  }
  for (int t = tid; t < 32 * 384; t += 256) {
    int c = t / 384, p = t % 384;
    int row = p >> 6, col = p & 63;
    int rg = r0 + row - 1;
    float val = 0.f;
    if ((unsigned)rg < 64u) {
      if (MODE == 0)
        val = xin[((size_t)b * 64 + ch0 + c) * HW + (rg << 6) + col] * alsh[c] + besh[c];
      else
        val = (float)(cin[((size_t)b * 32 + c) * HW + (rg << 6) + col]);
    }
    hsh[((size_t)row * 66 + col + 1) * 36 + c] = (_Float16)val;
  }
  __syncthreads();
  int w = tid >> 6, l = tid & 63;
  int ln = l & 15, g = l >> 4;
  // cache B-fragments (h) for this wave's row, 4 col-tiles x 9 taps
  H8 bfr[4][9];
  #pragma unroll
  for (int pf = 0; pf < 4; pf++)
    #pragma unroll
    for (int dyi = 0; dyi < 3; dyi++)
      #pragma unroll
      for (int dxi = 0; dxi < 3; dxi++) {
        const _Float16* p = &hsh[(((size_t)(w + dyi)) * 66 + pf * 16 + ln + dxi) * 36 + 4 * g];
        H8 f;
        f.q[0] = *(const ushort4*)p;
        f.q[1] = *(const ushort4*)(p + 16);
        bfr[pf][dyi * 3 + dxi] = f;
      }
  const _Float16* wb = wpk + ((MODE == 1) ? (size_t)b * NC_ALL * 9 * 64 * 8 : 0);
  int cbeg = bz * NC_HALF, cend = cbeg + NC_HALF;
  for (int chunk = cbeg; chunk < cend; chunk++) {
    H8 af[9];
    #pragma unroll
    for (int t = 0; t < 9; t++)
      af[t].u4 = *(const uint4*)(wb + (((size_t)chunk * 9 + t) * 64 + l) * 8);
    _Float16* ob; int Cb, ol0;
    if (MODE == 0) {
      if (chunk < 2)       { ob = o0; Cb = 32; ol0 = chunk * 16; }
      else if (chunk < 6)  { ob = o1; Cb = 64; ol0 = (chunk - 2) * 16; }
      else if (chunk < 8)  { ob = o2; Cb = 32; ol0 = (chunk - 6) * 16; }
      else if (chunk < 12) { ob = o3; Cb = 64; ol0 = (chunk - 8) * 16; }
      else                 { ob = o4; Cb = 32; ol0 = (chunk - 12) * 16; }
    } else { ob = o0; Cb = 64; ol0 = chunk * 16; }
    #pragma unroll
    for (int pf = 0; pf < 4; pf++) {
      f32x4 acc = {0.f, 0.f, 0.f, 0.f};
      #pragma unroll
      for (int t = 0; t < 9; t++)
        acc = __builtin_amdgcn_mfma_f32_16x16x32_f16(af[t].v, bfr[pf][t].v, acc, 0, 0, 0);
      int px = ((r0 + w) << 6) + pf * 16 + ln;
      #pragma unroll
      for (int j = 0; j < 4; j++) {
        int o = ol0 + 4 * g + j;
        ob[((size_t)b * Cb + o) * HW + px] = (_Float16)acc[j];
      }
    }
  }
}

// ---------------- attn k=3 partials: o-split, coalesced float4 writes ----------------
// grid (21, 32, 2): bx = rc*7+rg; bz = o-half. part1[bx][b][oh][cc][ol*32+i]
__global__ __launch_bounds__(256) void attn1_partial_kernel(
    const _Float16* __restrict__ y1, const _Float16* __restrict__ y2,
    float* __restrict__ part) {
  int rc = blockIdx.x / 7, rg = blockIdx.x % 7;
  int b = blockIdx.y, oh = blockIdx.z;
  __shared__ float s1[32][65];
  __shared__ float s2[32][65];
  int tid = threadIdx.x;
  int ol = tid >> 3;          // 0..31 (local o)
  int i0 = (tid & 7) * 4;     // 0,4,...,28
  int col = tid & 63, rw = tid >> 6;
  float acc[4][3] = {};
  const _Float16* y1b = y1 + (size_t)b * 32 * HW;
  const _Float16* y2b = y2 + ((size_t)b * 64 + oh * 32) * HW;
  for (int j = 0; j < 3; j++) {
    int r = rc + 9 * rg + 3 * j;
    __syncthreads();
    for (int c = rw; c < 32; c += 4) {
      s1[c][col] = (float)(y1b[(size_t)c * HW + (r << 6) + col]);
      s2[c][col] = (float)(y2b[(size_t)c * HW + (r << 6) + col]);
    }
    __syncthreads();
    for (int c3 = 0; c3 < 21; c3++) {
      #pragma unroll
      for (int cc = 0; cc < 3; cc++) {
        int c = 3 * c3 + cc;
        float yo = s2[ol][c];
        #pragma unroll
        for (int ii = 0; ii < 4; ii++) acc[ii][cc] += s1[i0 + ii][c] * yo;
      }
    }
  }
  size_t base = ((((size_t)blockIdx.x * 32 + b) * 2 + oh) * 3) * 1024 + ol * 32 + i0;
  #pragma unroll
  for (int cc = 0; cc < 3; cc++) {
    float4 v = {acc[0][cc], acc[1][cc], acc[2][cc], acc[3][cc]};
    *(float4*)&part[base + (size_t)cc * 1024] = v;
  }
}

// ---------------- attn k=1 partials: one 64-px tile per block (split-K=64) ----------------
__global__ __launch_bounds__(256) void attn2_partial_kernel(
    const _Float16* __restrict__ y1, const _Float16* __restrict__ y2,
    float* __restrict__ part) {
  int ps = blockIdx.x, b = blockIdx.y;  // ps 0..63
  __shared__ float s1[32][65];
  __shared__ float s2[64][65];
  int tid = threadIdx.x;
  int o = tid >> 2, i0 = (tid & 3) * 8;
  int col = tid & 63, rw = tid >> 6;
  const _Float16* y1b = y1 + (size_t)b * 32 * HW + ps * 64;
  const _Float16* y2b = y2 + (size_t)b * 64 * HW + ps * 64;
  for (int c = rw; c < 32; c += 4) s1[c][col] = (float)(y1b[(size_t)c * HW + col]);
  for (int c = rw; c < 64; c += 4) s2[c][col] = (float)(y2b[(size_t)c * HW + col]);
  __syncthreads();
  float acc[8] = {};
  #pragma unroll 8
  for (int p = 0; p < 64; p++) {
    float yo = s2[o][p];
    #pragma unroll
    for (int ii = 0; ii < 8; ii++) acc[ii] += s1[i0 + ii][p] * yo;
  }
  size_t base = ((size_t)ps * 32 + b) * 2048 + o * 32 + i0;
  for (int ii = 0; ii < 8; ii++) part[base + ii] = acc[ii];
}

// ---------------- fused: reduce partials + softmax(a2) + ak + pack to MFMA order ----------------
__global__ __launch_bounds__(320) void fused_ak_kernel(
    const float* __restrict__ part1, const float* __restrict__ part2,
    const float* __restrict__ aw, _Float16* __restrict__ wdyn) {
  int o = blockIdx.x, b = blockIdx.y;
  int tid = threadIdx.x;
  __shared__ float sm[33];
  if (tid < 32) {
    float s = 0.f;
    for (int ps = 0; ps < 64; ps++) s += part2[((size_t)ps * 32 + b) * 2048 + o * 32 + tid];
    sm[tid] = s * 0.17677669529663687f;  // 1/sqrt(32)
  }
  __syncthreads();
  if (tid == 0) {
    float mx = -1e30f;
    for (int k = 0; k < 32; k++) mx = fmaxf(mx, sm[k]);
    float sum = 0.f;
    for (int k = 0; k < 32; k++) { float e = expf(sm[k] - mx); sm[k] = e; sum += e; }
    sm[32] = 1.0f / sum;
  }
  __syncthreads();
  if (tid < 288) {
    int i = tid / 9, kk = tid % 9;
    int rc = kk / 3, cc = kk % 3;
    float a1v = 0.f;
    for (int rg = 0; rg < 7; rg++)
      a1v += part1[((((size_t)(rc * 7 + rg) * 32 + b) * 2 + (o >> 5)) * 3 + cc) * 1024 +
                   (o & 31) * 32 + i];
    a1v *= 0.05892556509887896f;  // 1/sqrt(288)
    float akv = sm[i] * sm[32] * (a1v + aw[(size_t)(o * 32 + i) * 9 + kk]);
    // pack directly into MFMA A-fragment order: wdyn[b][chunk][tap][lane][j]
    int chunk = o >> 4;
    int g = (i & 15) >> 2;
    int j = (i & 3) + ((i >= 16) ? 4 : 0);
    int lane = (g << 4) | (o & 15);
    wdyn[((((size_t)b * 4 + chunk) * 9 + kk) * 64 + lane) * 8 + j] = (_Float16)akv;
  }
}

// ---------------- output batchnorm affine + branch combine ----------------
__global__ __launch_bounds__(256) void finalize_kernel(
    const _Float16* __restrict__ v, const float* __restrict__ vmean,
    const float* __restrict__ vrstd, const float* __restrict__ a_post, int branch, int mode,
    float* __restrict__ acc, float* __restrict__ ysave,
    const float* __restrict__ x, const float* __restrict__ cm, float* __restrict__ out) {
  size_t idx = (size_t)blockIdx.x * 256 + threadIdx.x;  // B*64*HW
  int o = (int)((idx >> 12) & 63);
  float ap = a_post[branch];
  float ga = 0.5f * vrstd[o] + 0.6f * ap;
  float gb = -0.5f * vmean[o] * vrstd[o];
  float yv = ga * (float)(v[idx]) + gb;
  if (mode == 0) acc[idx] = yv;
  else if (mode == 1) acc[idx] += yv;
  else if (mode == 2) ysave[idx] = yv;
  else out[idx] = 0.99f * cm[0] * x[idx] + (acc[idx] + ysave[idx] * yv) * 0.5773502691896258f;
}

extern "C" void kernel_launch(void* const* d_in, const int* in_sizes, int n_in,
                              void* d_out, int out_size, void* d_ws, size_t ws_size,
                              hipStream_t stream) {
  const float* x      = (const float*)d_in[0];
  const float* wk1c1  = (const float*)d_in[1];
  const float* wk1c2  = (const float*)d_in[2];
  const float* wk2c1  = (const float*)d_in[3];
  const float* wk2c2  = (const float*)d_in[4];
  const float* wconv  = (const float*)d_in[5];
  const float* attn_w = (const float*)d_in[6];
  const float* a_pre  = (const float*)d_in[7];
  const float* a_post = (const float*)d_in[8];
  const float* cm     = (const float*)d_in[9];
  float* out = (float*)d_out;

  float* ws = (float*)d_ws;
  _Float16* y1a  = (_Float16*)(ws);             // 4,194,304 f16
  _Float16* y1b  = (_Float16*)(ws + 2097152);   // 8,388,608 f16
  _Float16* y2a  = (_Float16*)(ws + 6291456);   // 4,194,304 f16
  _Float16* y2b  = (_Float16*)(ws + 8388608);   // 8,388,608 f16
  _Float16* ccb  = (_Float16*)(ws + 12582912);  // 4,194,304 f16
  float* part1 = ws + 14680064;                 // 4,128,768 f32 (aliases vbuf slot)
  _Float16* vbuf = (_Float16*)part1;            // 8,388,608 f16
  float* part2 = ws + 2097152;                  // 4,194,304 f32 (aliases y1b slot; dead after attn1)
  _Float16* wpk  = (_Float16*)(ws + 19988480);  // 258,048 f16
  _Float16* wdyn = (_Float16*)(ws + 20117504);  // 589,824 f16
  float* accb  = ws + 20412416;                 // 8,388,608
  float* ysave = ws + 28801024;                 // 8,388,608
  float* xmean = ws + 37189632;
  float* xrstd = xmean + 64;
  float* vmean = xmean + 128;
  float* vrstd = xmean + 192;
  float* pstat  = xmean + 320;  // 1024

  bn_partial_kernel<float><<<dim3(64, 8), 256, 0, stream>>>(x, 64, pstat);
  bn_reduce_kernel<<<1, 64, 0, stream>>>(pstat, 32.f * HW, xmean, xrstd);
  pack_static_kernel<<<1008, 256, 0, stream>>>(wk1c1, wk1c2, wk2c1, wk2c2, wconv, wpk);

  for (int br = 0; br < 4; br++) {
    int ch0 = (br & 1) * 32;

    conv_mfma_kernel<0><<<dim3(16, 32, 2), 256, 0, stream>>>(
        x, ch0, nullptr, wpk + (size_t)br * 64512, xmean, xrstd, a_pre, br,
        y1a, y1b, y2a, y2b, ccb);

    // attn1 first (reads y1a/y1b), then attn2 (part2 overwrites the y1b slot)
    attn1_partial_kernel<<<dim3(21, 32, 2), 256, 0, stream>>>(y1a, y1b, part1);
    attn2_partial_kernel<<<dim3(64, 32), 256, 0, stream>>>(y2a, y2b, part2);
    fused_ak_kernel<<<dim3(64, 32), 320, 0, stream>>>(
        part1, part2, attn_w + (size_t)br * 64 * 288, wdyn);

    conv_mfma_kernel<1><<<dim3(16, 32, 2), 256, 0, stream>>>(
        nullptr, 0, ccb, wdyn, nullptr, nullptr, nullptr, 0,
        vbuf, nullptr, nullptr, nullptr, nullptr);

    bn_partial_kernel<_Float16><<<dim3(64, 8), 256, 0, stream>>>(vbuf, 64, pstat);
    bn_reduce_kernel<<<1, 64, 0, stream>>>(pstat, 32.f * HW, vmean, vrstd);
    finalize_kernel<<<32768, 256, 0, stream>>>(
        vbuf, vmean, vrstd, a_post, br, br, accb, ysave, x, cm, out);
  }
}

// Round 8
// 668.882 us; speedup vs baseline: 1.2799x; 1.2799x over previous
//
#include <hip/hip_runtime.h>
#include <math.h>

#define HW 4096
#define BB 32
#define EPSV 1e-5f

typedef _Float16 half8 __attribute__((ext_vector_type(8)));
typedef float f32x4 __attribute__((ext_vector_type(4)));
union H8 { half8 v; ushort4 q[2]; uint4 u4; };

__device__ __forceinline__ float tofloat(const float& v) { return v; }
__device__ __forceinline__ float tofloat(const _Float16& v) { return (float)v; }

// ---------------- bn stats: partial + reduce ----------------
template <typename T>
__global__ __launch_bounds__(256) void bn_partial_kernel(
    const T* __restrict__ x, int C, float* __restrict__ pstat) {
  int c = blockIdx.x, s = blockIdx.y;
  int tid = threadIdx.x;
  float sm = 0.f, s2 = 0.f;
  for (int b = s * 4; b < s * 4 + 4; b++) {
    const T* p = x + ((size_t)b * C + c) * HW;
    for (int i = tid; i < HW; i += 256) { float t = tofloat(p[i]); sm += t; s2 += t * t; }
  }
  __shared__ float sh[2][256];
  sh[0][tid] = sm; sh[1][tid] = s2;
  __syncthreads();
  for (int off = 128; off > 0; off >>= 1) {
    if (tid < off) { sh[0][tid] += sh[0][tid + off]; sh[1][tid] += sh[1][tid + off]; }
    __syncthreads();
  }
  if (tid == 0) {
    pstat[((size_t)s * 64 + c) * 2] = sh[0][0];
    pstat[((size_t)s * 64 + c) * 2 + 1] = sh[1][0];
  }
}

__global__ void bn_reduce_kernel(const float* __restrict__ pstat, float N,
                                 float* __restrict__ mean, float* __restrict__ rstd) {
  int c = threadIdx.x;  // 64
  float s = 0.f, s2 = 0.f;
  for (int k = 0; k < 8; k++) {
    s += pstat[((size_t)k * 64 + c) * 2];
    s2 += pstat[((size_t)k * 64 + c) * 2 + 1];
  }
  float m = s / N;
  mean[c] = m;
  rstd[c] = rsqrtf(s2 / N - m * m + EPSV);
}

// ---------------- pack static conv weights into MFMA A-fragment order ----------------
// wpk[br][chunk14][tap9][lane64][j8]; row o = chunk*16+(lane&15); k(c) = j<4 ? 4g+j : 16+4g+j-4
__global__ __launch_bounds__(256) void pack_static_kernel(
    const float* __restrict__ wk1c1, const float* __restrict__ wk1c2,
    const float* __restrict__ wk2c1, const float* __restrict__ wk2c2,
    const float* __restrict__ wconv, _Float16* __restrict__ wpk) {
  int idx = blockIdx.x * 256 + threadIdx.x;  // 258048
  int j = idx & 7, lane = (idx >> 3) & 63;
  int tap = (idx >> 9) % 9;
  int chunk = (idx / 4608) % 14;
  int br = idx / 64512;
  int g = lane >> 4;
  int c = (j < 4) ? 4 * g + j : 16 + 4 * g + (j - 4);
  const float* src; int ol0;
  if (chunk < 2)       { src = wk1c1 + (size_t)br * 32 * 288; ol0 = chunk * 16; }
  else if (chunk < 6)  { src = wk1c2 + (size_t)br * 64 * 288; ol0 = (chunk - 2) * 16; }
  else if (chunk < 8)  { src = wk2c1 + (size_t)br * 32 * 288; ol0 = (chunk - 6) * 16; }
  else if (chunk < 12) { src = wk2c2 + (size_t)br * 64 * 288; ol0 = (chunk - 8) * 16; }
  else                 { src = wconv + (size_t)br * 32 * 288; ol0 = (chunk - 12) * 16; }
  int o = ol0 + (lane & 15);
  wpk[idx] = (_Float16)(src[((size_t)o * 32 + c) * 9 + tap]);
}

// ---------------- MFMA conv: 9 shifted K=32 GEMMs ----------------
// MODE0 = 5 static convs (bn affine folded), MODE1 = per-sample dynamic conv.
// Swapped operands: D[px][ch] -> each thread stores 4 consecutive px (8B).
template <int MODE>
__global__ __launch_bounds__(256) void conv_mfma_kernel(
    const float* __restrict__ xin, int ch0,
    const _Float16* __restrict__ cin,
    const _Float16* __restrict__ wpk,
    const float* __restrict__ mean, const float* __restrict__ rstd,
    const float* __restrict__ a_pre, int branch,
    _Float16* __restrict__ o0, _Float16* __restrict__ o1,
    _Float16* __restrict__ o2, _Float16* __restrict__ o3,
    _Float16* __restrict__ o4) {
  const int NCHUNK = (MODE == 0) ? 14 : 4;
  __shared__ _Float16 hsh[6 * 66 * 36];  // [row6][col66][c-pad36]
  __shared__ float alsh[32], besh[32];
  int tid = threadIdx.x;
  int b = blockIdx.y, r0 = blockIdx.x * 4;
  if (MODE == 0 && tid < 32) {  // fold bn + shortcut into per-channel affine
    float ap = a_pre[branch];
    float r = rstd[ch0 + tid], m = mean[ch0 + tid];
    alsh[tid] = 0.5f * r + 0.01f * ap;
    besh[tid] = -0.5f * m * r;
  }
  __syncthreads();
  for (int t = tid; t < 384; t += 256) {  // zero halo cols
    int row = t >> 6, colh = ((t & 63) >> 5) ? 65 : 0, c = t & 31;
    hsh[(row * 66 + colh) * 36 + c] = (_Float16)0.f;
  }
  if (MODE == 0) {
    for (int t = tid; t < 32 * 96; t += 256) {  // float4-vectorized staging
      int c = t / 96, p4 = (t % 96) * 4;
      int row = p4 >> 6, col = p4 & 63;
      int rg = r0 + row - 1;
      float4 v4 = {0.f, 0.f, 0.f, 0.f};
      if ((unsigned)rg < 64u)
        v4 = *(const float4*)&xin[((size_t)b * 64 + ch0 + c) * HW + (rg << 6) + col];
      float a = alsh[c], be = besh[c];
      _Float16* dst = &hsh[((size_t)row * 66 + col + 1) * 36 + c];
      dst[0]   = (_Float16)(v4.x * a + be);
      dst[36]  = (_Float16)(v4.y * a + be);
      dst[72]  = (_Float16)(v4.z * a + be);
      dst[108] = (_Float16)(v4.w * a + be);
    }
  } else {
    for (int t = tid; t < 32 * 48; t += 256) {  // 16B-vectorized staging
      int c = t / 48, p8 = (t % 48) * 8;
      int row = p8 >> 6, col = p8 & 63;
      int rg = r0 + row - 1;
      H8 v; v.u4 = make_uint4(0, 0, 0, 0);
      if ((unsigned)rg < 64u)
        v.u4 = *(const uint4*)&cin[((size_t)b * 32 + c) * HW + (rg << 6) + col];
      _Float16* dst = &hsh[((size_t)row * 66 + col + 1) * 36 + c];
      #pragma unroll
      for (int k = 0; k < 8; k++) dst[36 * k] = v.v[k];
    }
  }
  __syncthreads();
  int w = tid >> 6, l = tid & 63;
  int ln = l & 15, g = l >> 4;
  // cache h-fragments for this wave's row: 4 col-tiles x 9 taps (used as A-operand)
  H8 bfr[4][9];
  #pragma unroll
  for (int pf = 0; pf < 4; pf++)
    #pragma unroll
    for (int dyi = 0; dyi < 3; dyi++)
      #pragma unroll
      for (int dxi = 0; dxi < 3; dxi++) {
        const _Float16* p = &hsh[(((size_t)(w + dyi)) * 66 + pf * 16 + ln + dxi) * 36 + 4 * g];
        H8 f;
        f.q[0] = *(const ushort4*)p;
        f.q[1] = *(const ushort4*)(p + 16);
        bfr[pf][dyi * 3 + dxi] = f;
      }
  const _Float16* wb = wpk + ((MODE == 1) ? (size_t)b * NCHUNK * 9 * 64 * 8 : 0);
  for (int chunk = 0; chunk < NCHUNK; chunk++) {
    H8 af[9];
    #pragma unroll
    for (int t = 0; t < 9; t++)
      af[t].u4 = *(const uint4*)(wb + (((size_t)chunk * 9 + t) * 64 + l) * 8);
    _Float16* ob; int Cb, ol0;
    if (MODE == 0) {
      if (chunk < 2)       { ob = o0; Cb = 32; ol0 = chunk * 16; }
      else if (chunk < 6)  { ob = o1; Cb = 64; ol0 = (chunk - 2) * 16; }
      else if (chunk < 8)  { ob = o2; Cb = 32; ol0 = (chunk - 6) * 16; }
      else if (chunk < 12) { ob = o3; Cb = 64; ol0 = (chunk - 8) * 16; }
      else                 { ob = o4; Cb = 32; ol0 = (chunk - 12) * 16; }
    } else { ob = o0; Cb = 64; ol0 = chunk * 16; }
    #pragma unroll
    for (int pf = 0; pf < 4; pf++) {
      f32x4 acc = {0.f, 0.f, 0.f, 0.f};
      #pragma unroll
      for (int t = 0; t < 9; t++)
        acc = __builtin_amdgcn_mfma_f32_16x16x32_f16(bfr[pf][t].v, af[t].v, acc, 0, 0, 0);
      // D[px][ch]: col=lane&15 -> channel ol0+ln, row=4g+j -> 4 consecutive px
      union { _Float16 h[4]; ushort4 u; } sv;
      #pragma unroll
      for (int j = 0; j < 4; j++) sv.h[j] = (_Float16)acc[j];
      int px = ((r0 + w) << 6) + pf * 16 + 4 * g;
      *(ushort4*)&ob[((size_t)b * Cb + ol0 + ln) * HW + px] = sv.u;
    }
  }
}

// ---------------- attn k=3 partials: o-split, coalesced float4 writes ----------------
// grid (21, 32, 2): bx = rc*7+rg; bz = o-half. part1[bx][b][oh][cc][ol*32+i]
__global__ __launch_bounds__(256) void attn1_partial_kernel(
    const _Float16* __restrict__ y1, const _Float16* __restrict__ y2,
    float* __restrict__ part) {
  int rc = blockIdx.x / 7, rg = blockIdx.x % 7;
  int b = blockIdx.y, oh = blockIdx.z;
  __shared__ float s1[32][65];
  __shared__ float s2[32][65];
  int tid = threadIdx.x;
  int ol = tid >> 3;          // 0..31 (local o)
  int i0 = (tid & 7) * 4;     // 0,4,...,28
  int col = tid & 63, rw = tid >> 6;
  float acc[4][3] = {};
  const _Float16* y1b = y1 + (size_t)b * 32 * HW;
  const _Float16* y2b = y2 + ((size_t)b * 64 + oh * 32) * HW;
  for (int j = 0; j < 3; j++) {
    int r = rc + 9 * rg + 3 * j;
    __syncthreads();
    for (int c = rw; c < 32; c += 4) {
      s1[c][col] = (float)(y1b[(size_t)c * HW + (r << 6) + col]);
      s2[c][col] = (float)(y2b[(size_t)c * HW + (r << 6) + col]);
    }
    __syncthreads();
    for (int c3 = 0; c3 < 21; c3++) {
      #pragma unroll
      for (int cc = 0; cc < 3; cc++) {
        int c = 3 * c3 + cc;
        float yo = s2[ol][c];
        #pragma unroll
        for (int ii = 0; ii < 4; ii++) acc[ii][cc] += s1[i0 + ii][c] * yo;
      }
    }
  }
  size_t base = ((((size_t)blockIdx.x * 32 + b) * 2 + oh) * 3) * 1024 + ol * 32 + i0;
  #pragma unroll
  for (int cc = 0; cc < 3; cc++) {
    float4 v = {acc[0][cc], acc[1][cc], acc[2][cc], acc[3][cc]};
    *(float4*)&part[base + (size_t)cc * 1024] = v;
  }
}

// ---------------- attn k=1 partials: one 64-px tile per block (split-K=64) ----------------
__global__ __launch_bounds__(256) void attn2_partial_kernel(
    const _Float16* __restrict__ y1, const _Float16* __restrict__ y2,
    float* __restrict__ part) {
  int ps = blockIdx.x, b = blockIdx.y;  // ps 0..63
  __shared__ float s1[32][65];
  __shared__ float s2[64][65];
  int tid = threadIdx.x;
  int o = tid >> 2, i0 = (tid & 3) * 8;
  int col = tid & 63, rw = tid >> 6;
  const _Float16* y1b = y1 + (size_t)b * 32 * HW + ps * 64;
  const _Float16* y2b = y2 + (size_t)b * 64 * HW + ps * 64;
  for (int c = rw; c < 32; c += 4) s1[c][col] = (float)(y1b[(size_t)c * HW + col]);
  for (int c = rw; c < 64; c += 4) s2[c][col] = (float)(y2b[(size_t)c * HW + col]);
  __syncthreads();
  float acc[8] = {};
  #pragma unroll 8
  for (int p = 0; p < 64; p++) {
    float yo = s2[o][p];
    #pragma unroll
    for (int ii = 0; ii < 8; ii++) acc[ii] += s1[i0 + ii][p] * yo;
  }
  size_t base = ((size_t)ps * 32 + b) * 2048 + o * 32 + i0;
  for (int ii = 0; ii < 8; ii++) part[base + ii] = acc[ii];
}

// ---------------- fused: reduce partials + softmax(a2) + ak + pack to MFMA order ----------------
__global__ __launch_bounds__(320) void fused_ak_kernel(
    const float* __restrict__ part1, const float* __restrict__ part2,
    const float* __restrict__ aw, _Float16* __restrict__ wdyn) {
  int o = blockIdx.x, b = blockIdx.y;
  int tid = threadIdx.x;
  __shared__ float sm[33];
  if (tid < 32) {
    float s = 0.f;
    for (int ps = 0; ps < 64; ps++) s += part2[((size_t)ps * 32 + b) * 2048 + o * 32 + tid];
    sm[tid] = s * 0.17677669529663687f;  // 1/sqrt(32)
  }
  __syncthreads();
  if (tid == 0) {
    float mx = -1e30f;
    for (int k = 0; k < 32; k++) mx = fmaxf(mx, sm[k]);
    float sum = 0.f;
    for (int k = 0; k < 32; k++) { float e = expf(sm[k] - mx); sm[k] = e; sum += e; }
    sm[32] = 1.0f / sum;
  }
  __syncthreads();
  if (tid < 288) {
    int i = tid / 9, kk = tid % 9;
    int rc = kk / 3, cc = kk % 3;
    float a1v = 0.f;
    for (int rg = 0; rg < 7; rg++)
      a1v += part1[((((size_t)(rc * 7 + rg) * 32 + b) * 2 + (o >> 5)) * 3 + cc) * 1024 +
                   (o & 31) * 32 + i];
    a1v *= 0.05892556509887896f;  // 1/sqrt(288)
    float akv = sm[i] * sm[32] * (a1v + aw[(size_t)(o * 32 + i) * 9 + kk]);
    // pack directly into MFMA A-fragment order: wdyn[b][chunk][tap][lane][j]
    int chunk = o >> 4;
    int g = (i & 15) >> 2;
    int j = (i & 3) + ((i >= 16) ? 4 : 0);
    int lane = (g << 4) | (o & 15);
    wdyn[((((size_t)b * 4 + chunk) * 9 + kk) * 64 + lane) * 8 + j] = (_Float16)akv;
  }
}

// ---------------- output batchnorm affine + branch combine ----------------
__global__ __launch_bounds__(256) void finalize_kernel(
    const _Float16* __restrict__ v, const float* __restrict__ vmean,
    const float* __restrict__ vrstd, const float* __restrict__ a_post, int branch, int mode,
    float* __restrict__ acc, float* __restrict__ ysave,
    const float* __restrict__ x, const float* __restrict__ cm, float* __restrict__ out) {
  size_t idx = (size_t)blockIdx.x * 256 + threadIdx.x;  // B*64*HW
  int o = (int)((idx >> 12) & 63);
  float ap = a_post[branch];
  float ga = 0.5f * vrstd[o] + 0.6f * ap;
  float gb = -0.5f * vmean[o] * vrstd[o];
  float yv = ga * (float)(v[idx]) + gb;
  if (mode == 0) acc[idx] = yv;
  else if (mode == 1) acc[idx] += yv;
  else if (mode == 2) ysave[idx] = yv;
  else out[idx] = 0.99f * cm[0] * x[idx] + (acc[idx] + ysave[idx] * yv) * 0.5773502691896258f;
}

extern "C" void kernel_launch(void* const* d_in, const int* in_sizes, int n_in,
                              void* d_out, int out_size, void* d_ws, size_t ws_size,
                              hipStream_t stream) {
  const float* x      = (const float*)d_in[0];
  const float* wk1c1  = (const float*)d_in[1];
  const float* wk1c2  = (const float*)d_in[2];
  const float* wk2c1  = (const float*)d_in[3];
  const float* wk2c2  = (const float*)d_in[4];
  const float* wconv  = (const float*)d_in[5];
  const float* attn_w = (const float*)d_in[6];
  const float* a_pre  = (const float*)d_in[7];
  const float* a_post = (const float*)d_in[8];
  const float* cm     = (const float*)d_in[9];
  float* out = (float*)d_out;

  float* ws = (float*)d_ws;
  _Float16* y1a  = (_Float16*)(ws);             // 4,194,304 f16
  _Float16* y1b  = (_Float16*)(ws + 2097152);   // 8,388,608 f16
  _Float16* y2a  = (_Float16*)(ws + 6291456);   // 4,194,304 f16
  _Float16* y2b  = (_Float16*)(ws + 8388608);   // 8,388,608 f16
  _Float16* ccb  = (_Float16*)(ws + 12582912);  // 4,194,304 f16
  float* part1 = ws + 14680064;                 // 4,128,768 f32 (aliases vbuf slot)
  _Float16* vbuf = (_Float16*)part1;            // 8,388,608 f16
  float* part2 = ws + 2097152;                  // 4,194,304 f32 (aliases y1b slot; dead after attn1)
  _Float16* wpk  = (_Float16*)(ws + 19988480);  // 258,048 f16
  _Float16* wdyn = (_Float16*)(ws + 20117504);  // 589,824 f16
  float* accb  = ws + 20412416;                 // 8,388,608
  float* ysave = ws + 28801024;                 // 8,388,608
  float* xmean = ws + 37189632;
  float* xrstd = xmean + 64;
  float* vmean = xmean + 128;
  float* vrstd = xmean + 192;
  float* pstat  = xmean + 320;  // 1024

  bn_partial_kernel<float><<<dim3(64, 8), 256, 0, stream>>>(x, 64, pstat);
  bn_reduce_kernel<<<1, 64, 0, stream>>>(pstat, 32.f * HW, xmean, xrstd);
  pack_static_kernel<<<1008, 256, 0, stream>>>(wk1c1, wk1c2, wk2c1, wk2c2, wconv, wpk);

  for (int br = 0; br < 4; br++) {
    int ch0 = (br & 1) * 32;

    conv_mfma_kernel<0><<<dim3(16, 32), 256, 0, stream>>>(
        x, ch0, nullptr, wpk + (size_t)br * 64512, xmean, xrstd, a_pre, br,
        y1a, y1b, y2a, y2b, ccb);

    // attn1 first (reads y1a/y1b), then attn2 (part2 overwrites the y1b slot)
    attn1_partial_kernel<<<dim3(21, 32, 2), 256, 0, stream>>>(y1a, y1b, part1);
    attn2_partial_kernel<<<dim3(64, 32), 256, 0, stream>>>(y2a, y2b, part2);
    fused_ak_kernel<<<dim3(64, 32), 320, 0, stream>>>(
        part1, part2, attn_w + (size_t)br * 64 * 288, wdyn);

    conv_mfma_kernel<1><<<dim3(16, 32), 256, 0, stream>>>(
        nullptr, 0, ccb, wdyn, nullptr, nullptr, nullptr, 0,
        vbuf, nullptr, nullptr, nullptr, nullptr);

    bn_partial_kernel<_Float16><<<dim3(64, 8), 256, 0, stream>>>(vbuf, 64, pstat);
    bn_reduce_kernel<<<1, 64, 0, stream>>>(pstat, 32.f * HW, vmean, vrstd);
    finalize_kernel<<<32768, 256, 0, stream>>>(
        vbuf, vmean, vrstd, a_post, br, br, accb, ysave, x, cm, out);
  }
}

// Round 9
// 539.388 us; speedup vs baseline: 1.5872x; 1.2401x over previous
//
#include <hip/hip_runtime.h>
#include <math.h>

#define HW 4096
#define BB 32
#define EPSV 1e-5f

typedef _Float16 half8 __attribute__((ext_vector_type(8)));
typedef float f32x4 __attribute__((ext_vector_type(4)));
union H8 { half8 v; ushort4 q[2]; uint4 u4; };

// slab layout (float offsets):
//   y1a @ 0         (32ch f16)   y2a @ 2097152  (32ch f16)
//   y1b @ 4194304   (64ch f16)   y2b @ 8388608  (64ch f16)
//   ccb @ 12582912  (32ch f16)   part1 @ 14680064 (f32)
//   part2 aliases y1b (dead after attn1)
#define SLAB_F 18808832ull
#define OFF_Y1A 0
#define OFF_Y2A 2097152
#define OFF_Y1B 4194304
#define OFF_Y2B 8388608
#define OFF_CCB 12582912
#define OFF_P1  14680064

// ---------------- bn stats over x ----------------
__global__ __launch_bounds__(256) void bn_partial_kernel(
    const float* __restrict__ x, float* __restrict__ pstat) {
  int c = blockIdx.x, s = blockIdx.y;
  int tid = threadIdx.x;
  float sm = 0.f, s2 = 0.f;
  for (int b = s * 4; b < s * 4 + 4; b++) {
    const float* p = x + ((size_t)b * 64 + c) * HW;
    for (int i = tid; i < HW; i += 256) { float t = p[i]; sm += t; s2 += t * t; }
  }
  __shared__ float sh[2][256];
  sh[0][tid] = sm; sh[1][tid] = s2;
  __syncthreads();
  for (int off = 128; off > 0; off >>= 1) {
    if (tid < off) { sh[0][tid] += sh[0][tid + off]; sh[1][tid] += sh[1][tid + off]; }
    __syncthreads();
  }
  if (tid == 0) {
    pstat[((size_t)s * 64 + c) * 2] = sh[0][0];
    pstat[((size_t)s * 64 + c) * 2 + 1] = sh[1][0];
  }
}

// ---------------- bn stats over the 4 vbufs (f16, 8-wide loads) ----------------
__global__ __launch_bounds__(256) void bnv_partial_kernel(
    const _Float16* __restrict__ vbufB, float* __restrict__ pstat) {
  int c = blockIdx.x, s = blockIdx.y, br = blockIdx.z;
  int tid = threadIdx.x;
  const _Float16* vb = vbufB + (size_t)br * 8388608;
  float sm = 0.f, s2 = 0.f;
  for (int b = s * 4; b < s * 4 + 4; b++) {
    const _Float16* row = vb + ((size_t)b * 64 + c) * HW;
    for (int i = tid; i < 512; i += 256) {
      H8 v; v.u4 = *(const uint4*)(row + i * 8);
      #pragma unroll
      for (int k = 0; k < 8; k++) { float t = (float)v.v[k]; sm += t; s2 += t * t; }
    }
  }
  __shared__ float sh[2][256];
  sh[0][tid] = sm; sh[1][tid] = s2;
  __syncthreads();
  for (int off = 128; off > 0; off >>= 1) {
    if (tid < off) { sh[0][tid] += sh[0][tid + off]; sh[1][tid] += sh[1][tid + off]; }
    __syncthreads();
  }
  if (tid == 0) {
    pstat[(((size_t)br * 8 + s) * 64 + c) * 2] = sh[0][0];
    pstat[(((size_t)br * 8 + s) * 64 + c) * 2 + 1] = sh[1][0];
  }
}

// threads = nch (64 for x, 256 for v); pstat base (t>>6)*512 + (t&63), 8 sets stride 64
__global__ void bn_reduce_kernel(const float* __restrict__ pstat, float N,
                                 float* __restrict__ mean, float* __restrict__ rstd) {
  int t = threadIdx.x;
  int base = (t >> 6) * 512 + (t & 63);
  float s = 0.f, s2 = 0.f;
  for (int k = 0; k < 8; k++) {
    s += pstat[(size_t)(base + k * 64) * 2];
    s2 += pstat[(size_t)(base + k * 64) * 2 + 1];
  }
  float m = s / N;
  mean[t] = m;
  rstd[t] = rsqrtf(s2 / N - m * m + EPSV);
}

// ---------------- pack static conv weights into MFMA A-fragment order ----------------
__global__ __launch_bounds__(256) void pack_static_kernel(
    const float* __restrict__ wk1c1, const float* __restrict__ wk1c2,
    const float* __restrict__ wk2c1, const float* __restrict__ wk2c2,
    const float* __restrict__ wconv, _Float16* __restrict__ wpk) {
  int idx = blockIdx.x * 256 + threadIdx.x;  // 258048
  int j = idx & 7, lane = (idx >> 3) & 63;
  int tap = (idx >> 9) % 9;
  int chunk = (idx / 4608) % 14;
  int br = idx / 64512;
  int g = lane >> 4;
  int c = (j < 4) ? 4 * g + j : 16 + 4 * g + (j - 4);
  const float* src; int ol0;
  if (chunk < 2)       { src = wk1c1 + (size_t)br * 32 * 288; ol0 = chunk * 16; }
  else if (chunk < 6)  { src = wk1c2 + (size_t)br * 64 * 288; ol0 = (chunk - 2) * 16; }
  else if (chunk < 8)  { src = wk2c1 + (size_t)br * 32 * 288; ol0 = (chunk - 6) * 16; }
  else if (chunk < 12) { src = wk2c2 + (size_t)br * 64 * 288; ol0 = (chunk - 8) * 16; }
  else                 { src = wconv + (size_t)br * 32 * 288; ol0 = (chunk - 12) * 16; }
  int o = ol0 + (lane & 15);
  wpk[idx] = (_Float16)(src[((size_t)o * 32 + c) * 9 + tap]);
}

// ---------------- MFMA conv: 9 shifted K=32 GEMMs; branch via blockIdx.z ----------------
template <int MODE>
__global__ __launch_bounds__(256) void conv_mfma_kernel(
    const float* __restrict__ xin, const _Float16* __restrict__ wAll,
    const float* __restrict__ mean, const float* __restrict__ rstd,
    const float* __restrict__ a_pre,
    int brBase, float* __restrict__ slabBase, size_t slabStride,
    _Float16* __restrict__ vbufB) {
  const int NCHUNK = (MODE == 0) ? 14 : 4;
  int bz = blockIdx.z;
  int br = brBase + bz;
  float* slab = slabBase + (size_t)bz * slabStride;
  __shared__ _Float16 hsh[6 * 66 * 36];  // [row6][col66][c-pad36]
  __shared__ float alsh[32], besh[32];
  int tid = threadIdx.x;
  int b = blockIdx.y, r0 = blockIdx.x * 4;
  int ch0 = (br & 1) * 32;
  if (MODE == 0 && tid < 32) {
    float ap = a_pre[br];
    float r = rstd[ch0 + tid], m = mean[ch0 + tid];
    alsh[tid] = 0.5f * r + 0.01f * ap;
    besh[tid] = -0.5f * m * r;
  }
  __syncthreads();
  for (int t = tid; t < 384; t += 256) {  // zero halo cols
    int row = t >> 6, colh = ((t & 63) >> 5) ? 65 : 0, c = t & 31;
    hsh[(row * 66 + colh) * 36 + c] = (_Float16)0.f;
  }
  if (MODE == 0) {
    for (int t = tid; t < 32 * 96; t += 256) {  // float4 staging + affine
      int c = t / 96, p4 = (t % 96) * 4;
      int row = p4 >> 6, col = p4 & 63;
      int rg = r0 + row - 1;
      float4 v4 = {0.f, 0.f, 0.f, 0.f};
      if ((unsigned)rg < 64u)
        v4 = *(const float4*)&xin[((size_t)b * 64 + ch0 + c) * HW + (rg << 6) + col];
      float a = alsh[c], be = besh[c];
      _Float16* dst = &hsh[((size_t)row * 66 + col + 1) * 36 + c];
      dst[0]   = (_Float16)(v4.x * a + be);
      dst[36]  = (_Float16)(v4.y * a + be);
      dst[72]  = (_Float16)(v4.z * a + be);
      dst[108] = (_Float16)(v4.w * a + be);
    }
  } else {
    const _Float16* cin = (const _Float16*)(slab + OFF_CCB);
    for (int t = tid; t < 32 * 48; t += 256) {  // 16B staging
      int c = t / 48, p8 = (t % 48) * 8;
      int row = p8 >> 6, col = p8 & 63;
      int rg = r0 + row - 1;
      H8 v; v.u4 = make_uint4(0, 0, 0, 0);
      if ((unsigned)rg < 64u)
        v.u4 = *(const uint4*)&cin[((size_t)b * 32 + c) * HW + (rg << 6) + col];
      _Float16* dst = &hsh[((size_t)row * 66 + col + 1) * 36 + c];
      #pragma unroll
      for (int k = 0; k < 8; k++) dst[36 * k] = v.v[k];
    }
  }
  __syncthreads();
  int w = tid >> 6, l = tid & 63;
  int ln = l & 15, g = l >> 4;
  H8 bfr[4][9];
  #pragma unroll
  for (int pf = 0; pf < 4; pf++)
    #pragma unroll
    for (int dyi = 0; dyi < 3; dyi++)
      #pragma unroll
      for (int dxi = 0; dxi < 3; dxi++) {
        const _Float16* p = &hsh[(((size_t)(w + dyi)) * 66 + pf * 16 + ln + dxi) * 36 + 4 * g];
        H8 f;
        f.q[0] = *(const ushort4*)p;
        f.q[1] = *(const ushort4*)(p + 16);
        bfr[pf][dyi * 3 + dxi] = f;
      }
  const _Float16* wb = (MODE == 0)
      ? wAll + (size_t)br * 64512
      : wAll + (size_t)br * 589824 + (size_t)b * 18432;
  for (int chunk = 0; chunk < NCHUNK; chunk++) {
    H8 af[9];
    #pragma unroll
    for (int t = 0; t < 9; t++)
      af[t].u4 = *(const uint4*)(wb + (((size_t)chunk * 9 + t) * 64 + l) * 8);
    _Float16* ob; int Cb, ol0;
    if (MODE == 0) {
      if (chunk < 2)       { ob = (_Float16*)(slab + OFF_Y1A); Cb = 32; ol0 = chunk * 16; }
      else if (chunk < 6)  { ob = (_Float16*)(slab + OFF_Y1B); Cb = 64; ol0 = (chunk - 2) * 16; }
      else if (chunk < 8)  { ob = (_Float16*)(slab + OFF_Y2A); Cb = 32; ol0 = (chunk - 6) * 16; }
      else if (chunk < 12) { ob = (_Float16*)(slab + OFF_Y2B); Cb = 64; ol0 = (chunk - 8) * 16; }
      else                 { ob = (_Float16*)(slab + OFF_CCB); Cb = 32; ol0 = (chunk - 12) * 16; }
    } else { ob = vbufB + (size_t)br * 8388608; Cb = 64; ol0 = chunk * 16; }
    #pragma unroll
    for (int pf = 0; pf < 4; pf++) {
      f32x4 acc = {0.f, 0.f, 0.f, 0.f};
      #pragma unroll
      for (int t = 0; t < 9; t++)
        acc = __builtin_amdgcn_mfma_f32_16x16x32_f16(bfr[pf][t].v, af[t].v, acc, 0, 0, 0);
      union { _Float16 h[4]; ushort4 u; } sv;
      #pragma unroll
      for (int j = 0; j < 4; j++) sv.h[j] = (_Float16)acc[j];
      int px = ((r0 + w) << 6) + pf * 16 + 4 * g;
      *(ushort4*)&ob[((size_t)b * Cb + ol0 + ln) * HW + px] = sv.u;
    }
  }
}

// ---------------- attn k=3 partials ----------------
// grid (21, 32, 2*nbr): z = slabIdx*2 + oh
__global__ __launch_bounds__(256) void attn1_partial_kernel(
    float* __restrict__ slabBase, size_t slabStride) {
  int rc = blockIdx.x / 7, rg = blockIdx.x % 7;
  int b = blockIdx.y, oh = blockIdx.z & 1;
  float* slab = slabBase + (size_t)(blockIdx.z >> 1) * slabStride;
  const _Float16* y1 = (const _Float16*)(slab + OFF_Y1A);
  const _Float16* y2 = (const _Float16*)(slab + OFF_Y1B);
  float* part = slab + OFF_P1;
  __shared__ float s1[32][65];
  __shared__ float s2[32][65];
  int tid = threadIdx.x;
  int ol = tid >> 3;
  int i0 = (tid & 7) * 4;
  int col = tid & 63, rw = tid >> 6;
  float acc[4][3] = {};
  const _Float16* y1b = y1 + (size_t)b * 32 * HW;
  const _Float16* y2b = y2 + ((size_t)b * 64 + oh * 32) * HW;
  for (int j = 0; j < 3; j++) {
    int r = rc + 9 * rg + 3 * j;
    __syncthreads();
    for (int c = rw; c < 32; c += 4) {
      s1[c][col] = (float)(y1b[(size_t)c * HW + (r << 6) + col]);
      s2[c][col] = (float)(y2b[(size_t)c * HW + (r << 6) + col]);
    }
    __syncthreads();
    for (int c3 = 0; c3 < 21; c3++) {
      #pragma unroll
      for (int cc = 0; cc < 3; cc++) {
        int c = 3 * c3 + cc;
        float yo = s2[ol][c];
        #pragma unroll
        for (int ii = 0; ii < 4; ii++) acc[ii][cc] += s1[i0 + ii][c] * yo;
      }
    }
  }
  size_t base = ((((size_t)blockIdx.x * 32 + b) * 2 + oh) * 3) * 1024 + ol * 32 + i0;
  #pragma unroll
  for (int cc = 0; cc < 3; cc++) {
    float4 v = {acc[0][cc], acc[1][cc], acc[2][cc], acc[3][cc]};
    *(float4*)&part[base + (size_t)cc * 1024] = v;
  }
}

// ---------------- attn k=1 partials ----------------
// grid (64, 32, nbr)
__global__ __launch_bounds__(256) void attn2_partial_kernel(
    float* __restrict__ slabBase, size_t slabStride) {
  int ps = blockIdx.x, b = blockIdx.y;
  float* slab = slabBase + (size_t)blockIdx.z * slabStride;
  const _Float16* y1 = (const _Float16*)(slab + OFF_Y2A);
  const _Float16* y2 = (const _Float16*)(slab + OFF_Y2B);
  float* part = slab + OFF_Y1B;  // part2 aliases y1b
  __shared__ float s1[32][65];
  __shared__ float s2[64][65];
  int tid = threadIdx.x;
  int o = tid >> 2, i0 = (tid & 3) * 8;
  int col = tid & 63, rw = tid >> 6;
  const _Float16* y1b = y1 + (size_t)b * 32 * HW + ps * 64;
  const _Float16* y2b = y2 + (size_t)b * 64 * HW + ps * 64;
  for (int c = rw; c < 32; c += 4) s1[c][col] = (float)(y1b[(size_t)c * HW + col]);
  for (int c = rw; c < 64; c += 4) s2[c][col] = (float)(y2b[(size_t)c * HW + col]);
  __syncthreads();
  float acc[8] = {};
  #pragma unroll 8
  for (int p = 0; p < 64; p++) {
    float yo = s2[o][p];
    #pragma unroll
    for (int ii = 0; ii < 8; ii++) acc[ii] += s1[i0 + ii][p] * yo;
  }
  size_t base = ((size_t)ps * 32 + b) * 2048 + o * 32 + i0;
  for (int ii = 0; ii < 8; ii++) part[base + ii] = acc[ii];
}

// ---------------- fused: reduce partials + softmax + ak + pack ----------------
// grid (64, 32, nbr), 320 threads
__global__ __launch_bounds__(320) void fused_ak_kernel(
    float* __restrict__ slabBase, size_t slabStride, int brBase,
    const float* __restrict__ aw, _Float16* __restrict__ wdynB) {
  int o = blockIdx.x, b = blockIdx.y;
  int bz = blockIdx.z, br = brBase + bz;
  float* slab = slabBase + (size_t)bz * slabStride;
  const float* part1 = slab + OFF_P1;
  const float* part2 = slab + OFF_Y1B;
  const float* awb = aw + (size_t)br * 18432;
  _Float16* wdyn = wdynB + (size_t)br * 589824;
  int tid = threadIdx.x;
  __shared__ float sm[33];
  if (tid < 32) {
    float s = 0.f;
    for (int ps = 0; ps < 64; ps++) s += part2[((size_t)ps * 32 + b) * 2048 + o * 32 + tid];
    sm[tid] = s * 0.17677669529663687f;  // 1/sqrt(32)
  }
  __syncthreads();
  if (tid == 0) {
    float mx = -1e30f;
    for (int k = 0; k < 32; k++) mx = fmaxf(mx, sm[k]);
    float sum = 0.f;
    for (int k = 0; k < 32; k++) { float e = expf(sm[k] - mx); sm[k] = e; sum += e; }
    sm[32] = 1.0f / sum;
  }
  __syncthreads();
  if (tid < 288) {
    int i = tid / 9, kk = tid % 9;
    int rc = kk / 3, cc = kk % 3;
    float a1v = 0.f;
    for (int rg = 0; rg < 7; rg++)
      a1v += part1[((((size_t)(rc * 7 + rg) * 32 + b) * 2 + (o >> 5)) * 3 + cc) * 1024 +
                   (o & 31) * 32 + i];
    a1v *= 0.05892556509887896f;  // 1/sqrt(288)
    float akv = sm[i] * sm[32] * (a1v + awb[(size_t)(o * 32 + i) * 9 + kk]);
    int chunk = o >> 4;
    int g = (i & 15) >> 2;
    int j = (i & 3) + ((i >= 16) ? 4 : 0);
    int lane = (g << 4) | (o & 15);
    wdyn[((((size_t)b * 4 + chunk) * 9 + kk) * 64 + lane) * 8 + j] = (_Float16)akv;
  }
}

// ---------------- single fused finalize: 4-branch combine ----------------
// grid 4096 x 256: 8 px/thread
__global__ __launch_bounds__(256) void finalize_kernel(
    const _Float16* __restrict__ vbufB,
    const float* __restrict__ vmean, const float* __restrict__ vrstd,
    const float* __restrict__ a_post,
    const float* __restrict__ x, const float* __restrict__ cm,
    float* __restrict__ out) {
  size_t g8 = ((size_t)blockIdx.x * 256 + threadIdx.x) * 8;
  int o = (int)((g8 >> 12) & 63);
  float acc[8], ysv[8];
  #pragma unroll
  for (int br = 0; br < 4; br++) {
    float r = vrstd[br * 64 + o];
    float ga = 0.5f * r + 0.6f * a_post[br];
    float gb = -0.5f * vmean[br * 64 + o] * r;
    H8 v; v.u4 = *(const uint4*)(vbufB + (size_t)br * 8388608 + g8);
    #pragma unroll
    for (int j = 0; j < 8; j++) {
      float y = ga * (float)v.v[j] + gb;
      if (br == 0) acc[j] = y;
      else if (br == 1) acc[j] += y;
      else if (br == 2) ysv[j] = y;
      else acc[j] += ysv[j] * y;
    }
  }
  float cmv = 0.99f * cm[0];
  const float4* xp = (const float4*)(x + g8);
  float4 x0 = xp[0], x1 = xp[1];
  float4 o0, o1;
  o0.x = cmv * x0.x + acc[0] * 0.5773502691896258f;
  o0.y = cmv * x0.y + acc[1] * 0.5773502691896258f;
  o0.z = cmv * x0.z + acc[2] * 0.5773502691896258f;
  o0.w = cmv * x0.w + acc[3] * 0.5773502691896258f;
  o1.x = cmv * x1.x + acc[4] * 0.5773502691896258f;
  o1.y = cmv * x1.y + acc[5] * 0.5773502691896258f;
  o1.z = cmv * x1.z + acc[6] * 0.5773502691896258f;
  o1.w = cmv * x1.w + acc[7] * 0.5773502691896258f;
  float4* op = (float4*)(out + g8);
  op[0] = o0;
  op[1] = o1;
}

extern "C" void kernel_launch(void* const* d_in, const int* in_sizes, int n_in,
                              void* d_out, int out_size, void* d_ws, size_t ws_size,
                              hipStream_t stream) {
  const float* x      = (const float*)d_in[0];
  const float* wk1c1  = (const float*)d_in[1];
  const float* wk1c2  = (const float*)d_in[2];
  const float* wk2c1  = (const float*)d_in[3];
  const float* wk2c2  = (const float*)d_in[4];
  const float* wconv  = (const float*)d_in[5];
  const float* attn_w = (const float*)d_in[6];
  const float* a_pre  = (const float*)d_in[7];
  const float* a_post = (const float*)d_in[8];
  const float* cm     = (const float*)d_in[9];
  float* out = (float*)d_out;

  // batched (4 slabs) if workspace allows, else sequential (1 slab)
  const size_t needFloats = 4 * SLAB_F + 16777216ull + 129024 + 1179648 + 8192;
  bool batched = ws_size >= needFloats * 4;
  size_t nslab = batched ? 4 : 1;

  float* ws = (float*)d_ws;
  float* slab0 = ws;
  float* vbufF = ws + nslab * SLAB_F;
  _Float16* vbufB = (_Float16*)vbufF;
  _Float16* wpk   = (_Float16*)(vbufF + 16777216);
  _Float16* wdynB = (_Float16*)(vbufF + 16777216 + 129024);
  float* xmean = vbufF + 16777216 + 129024 + 1179648;
  float* xrstd = xmean + 64;
  float* vmean = xmean + 128;   // 256
  float* vrstd = xmean + 384;   // 256
  float* pstat = xmean + 640;   // 4096

  size_t SS = batched ? SLAB_F : 0;  // slab stride

  bn_partial_kernel<<<dim3(64, 8), 256, 0, stream>>>(x, pstat);
  bn_reduce_kernel<<<1, 64, 0, stream>>>(pstat, 32.f * HW, xmean, xrstd);
  pack_static_kernel<<<1008, 256, 0, stream>>>(wk1c1, wk1c2, wk2c1, wk2c2, wconv, wpk);

  if (batched) {
    conv_mfma_kernel<0><<<dim3(16, 32, 4), 256, 0, stream>>>(
        x, wpk, xmean, xrstd, a_pre, 0, slab0, SS, vbufB);
    attn1_partial_kernel<<<dim3(21, 32, 8), 256, 0, stream>>>(slab0, SS);
    attn2_partial_kernel<<<dim3(64, 32, 4), 256, 0, stream>>>(slab0, SS);
    fused_ak_kernel<<<dim3(64, 32, 4), 320, 0, stream>>>(slab0, SS, 0, attn_w, wdynB);
    conv_mfma_kernel<1><<<dim3(16, 32, 4), 256, 0, stream>>>(
        nullptr, wdynB, nullptr, nullptr, nullptr, 0, slab0, SS, vbufB);
  } else {
    for (int br = 0; br < 4; br++) {
      conv_mfma_kernel<0><<<dim3(16, 32, 1), 256, 0, stream>>>(
          x, wpk, xmean, xrstd, a_pre, br, slab0, 0, vbufB);
      attn1_partial_kernel<<<dim3(21, 32, 2), 256, 0, stream>>>(slab0, 0);
      attn2_partial_kernel<<<dim3(64, 32, 1), 256, 0, stream>>>(slab0, 0);
      fused_ak_kernel<<<dim3(64, 32, 1), 320, 0, stream>>>(slab0, 0, br, attn_w, wdynB);
      conv_mfma_kernel<1><<<dim3(16, 32, 1), 256, 0, stream>>>(
          nullptr, wdynB, nullptr, nullptr, nullptr, br, slab0, 0, vbufB);
    }
  }

  bnv_partial_kernel<<<dim3(64, 8, 4), 256, 0, stream>>>(vbufB, pstat);
  bn_reduce_kernel<<<1, 256, 0, stream>>>(pstat, 32.f * HW, vmean, vrstd);
  finalize_kernel<<<4096, 256, 0, stream>>>(vbufB, vmean, vrstd, a_post, x, cm, out);
}